// Round 9
// baseline (8747.650 us; speedup 1.0000x reference)
//
#include <hip/hip_runtime.h>
#include <stdint.h>

#define T_DIM 512
#define B_DIM 64
#define I_DIM 512
#define H_DIM 1024
#define BH ((size_t)B_DIM * H_DIM)
#define NW0 32   // layer-0 workgroups, 32 output cols each
#define NW1 32   // layer-1 workgroups, 32 output cols each

typedef __attribute__((ext_vector_type(8))) short short8;
typedef __attribute__((ext_vector_type(4))) float f32x4;

__device__ __forceinline__ unsigned short f2bf(float f) {
    unsigned int u = __float_as_uint(f);
    unsigned int r = (u + 0x7FFFu + ((u >> 16) & 1u)) >> 16;
    return (unsigned short)r;
}
__device__ __forceinline__ float bf2f(unsigned short b) {
    return __uint_as_float(((unsigned int)b) << 16);
}
__device__ __forceinline__ float fast_tanh(float x) {
    x = fminf(fmaxf(x, -15.f), 15.f);
    float e = __expf(2.f * x);
    return (e - 1.f) / (e + 1.f);
}

// ---- MALL-coherent (agent-scope, L1/L2-bypassing) data path ----
__device__ __forceinline__ unsigned long long ld64_sys(const unsigned short* p) {
    return __hip_atomic_load((const unsigned long long*)p, __ATOMIC_RELAXED,
                             __HIP_MEMORY_SCOPE_AGENT);
}
__device__ __forceinline__ short8 ldA_sys(const unsigned short* p) {
    union { unsigned long long u[2]; short8 v; } t;
    t.u[0] = ld64_sys(p);
    t.u[1] = ld64_sys(p + 4);
    return t.v;
}
__device__ __forceinline__ void st64_sys(unsigned short* p, unsigned long long v) {
    __hip_atomic_store((unsigned long long*)p, v, __ATOMIC_RELAXED,
                       __HIP_MEMORY_SCOPE_AGENT);
}
__device__ __forceinline__ void spin1(const int* f) {
    while (__hip_atomic_load(f, __ATOMIC_RELAXED, __HIP_MEMORY_SCOPE_AGENT) == 0)
        __builtin_amdgcn_s_sleep(1);
}

// ---------------- f32 -> bf16 convert, vectorized x4 ----------------
__global__ void conv_f2bf(const float* __restrict__ in, unsigned short* __restrict__ out, int n4) {
    int i = blockIdx.x * blockDim.x + threadIdx.x;
    int stride = gridDim.x * blockDim.x;
    for (int idx = i; idx < n4; idx += stride) {
        float4 v = reinterpret_cast<const float4*>(in)[idx];
        ushort4 o;
        o.x = f2bf(v.x); o.y = f2bf(v.y); o.z = f2bf(v.z); o.w = f2bf(v.w);
        reinterpret_cast<ushort4*>(out)[idx] = o;
    }
}

__global__ void bias_sum(const float* __restrict__ a, const float* __restrict__ b,
                         float* __restrict__ o, int n) {
    int i = blockIdx.x * blockDim.x + threadIdx.x;
    if (i < n) o[i] = a[i] + b[i];
}

// ---------------- GEMM: C[M,N] = A[M,K] @ W[N,K]^T + bias[N] ----------------
template <int OUT_BF16>
__global__ void gemm_bias(const unsigned short* __restrict__ A,
                          const unsigned short* __restrict__ W,
                          const float* __restrict__ bias,
                          void* __restrict__ Cout,
                          int M, int N, int K) {
    const int ntn = N >> 6;
    const int mt = blockIdx.x / ntn;
    const int nt = blockIdx.x % ntn;
    const int m_base = mt << 6, n_base = nt << 6;
    const int lane = threadIdx.x & 63;
    const int wave = threadIdx.x >> 6;
    const int wm = wave >> 1, wn = wave & 1;
    const int r0 = lane & 15;
    const int g  = lane >> 4;
    const int koff = g << 3;

    f32x4 acc[2][2];
    for (int i = 0; i < 2; i++)
        for (int j = 0; j < 2; j++)
            acc[i][j] = (f32x4)(0.f);

    const unsigned short* Arow0 = A + (size_t)(m_base + wm * 32 + r0) * K + koff;
    const unsigned short* Wrow0 = W + (size_t)(n_base + wn * 32 + r0) * K + koff;

    for (int k0 = 0; k0 < K; k0 += 32) {
        short8 a0 = *reinterpret_cast<const short8*>(Arow0 + k0);
        short8 a1 = *reinterpret_cast<const short8*>(Arow0 + (size_t)16 * K + k0);
        short8 b0 = *reinterpret_cast<const short8*>(Wrow0 + k0);
        short8 b1 = *reinterpret_cast<const short8*>(Wrow0 + (size_t)16 * K + k0);
        acc[0][0] = __builtin_amdgcn_mfma_f32_16x16x32_bf16(a0, b0, acc[0][0], 0, 0, 0);
        acc[0][1] = __builtin_amdgcn_mfma_f32_16x16x32_bf16(a0, b1, acc[0][1], 0, 0, 0);
        acc[1][0] = __builtin_amdgcn_mfma_f32_16x16x32_bf16(a1, b0, acc[1][0], 0, 0, 0);
        acc[1][1] = __builtin_amdgcn_mfma_f32_16x16x32_bf16(a1, b1, acc[1][1], 0, 0, 0);
    }

    for (int mi = 0; mi < 2; mi++) {
        for (int ni = 0; ni < 2; ni++) {
            for (int r = 0; r < 4; r++) {
                int row = m_base + wm * 32 + mi * 16 + g * 4 + r;
                int col = n_base + wn * 32 + ni * 16 + r0;
                float v = acc[mi][ni][r] + bias[col];
                if (OUT_BF16)
                    ((unsigned short*)Cout)[(size_t)row * N + col] = f2bf(v);
                else
                    ((float*)Cout)[(size_t)row * N + col] = v;
            }
        }
    }
}

// ---------------- persistent pipelined 2-layer RNN recurrence ----------------
// 64 wgs x 256 thr, cooperative. wg<32: layer0 (32 cols, W_hh0 slice 64KB LDS).
// wg>=32: layer1 (32 cols, [W_ih1|W_hh1] slice 128KB LDS, K=2048).
// Weight LDS layout: 16B chunk (kc,c) at (kc*32+c)*16 -> B-frag ds_read_b128
// per quarter-wave hits distinct banks (2-way max).
// Cross-step data moves ONLY via agent-scope atomics (MALL-coherent, no
// L2 writeback/invalidate fences). Epilogue transposes C-frags through a
// per-wave LDS scratch so each lane stores 8 contiguous bf16 (2x b64).
__global__ void __launch_bounds__(256, 1)
rnn_persist(const unsigned short* __restrict__ xp0,
            const unsigned short* __restrict__ whh0,
            const unsigned short* __restrict__ wih1,
            const unsigned short* __restrict__ whh1,
            const float* __restrict__ bias1,
            const unsigned short* __restrict__ hinit,
            unsigned short* __restrict__ out0,
            unsigned short* __restrict__ out1,
            int* __restrict__ flags0,
            int* __restrict__ flags1)
{
    __shared__ __attribute__((aligned(16))) char smem[140288];  // 128K weights + 9K scratch
    const int tid  = threadIdx.x;
    const int lane = tid & 63;
    const int wave = tid >> 6;
    const int r0 = lane & 15;
    const int g  = lane >> 4;
    const int wg = blockIdx.x;
    const int brow = (wave << 4) + r0;

    const char* Bp = smem + (g << 9) + (r0 << 4);          // + s*2048 + nf*256
    float* sc = (float*)(smem + 131072) + wave * 576;       // 16 rows x 36 f32
    const int rr = lane >> 2;                               // epilogue row 0..15
    const int cc = (lane & 3) << 3;                         // epilogue col base (8 wide)
    const int orow = (wave << 4) + rr;

    if (wg < NW0) {
        const int n0 = wg << 5;
        for (int i = tid; i < 4096; i += 256) {             // 32 cols x 128 kc
            const int c = i & 31, kc = i >> 5;
            *reinterpret_cast<short8*>(smem + (((kc << 5) + c) << 4)) =
                *reinterpret_cast<const short8*>(whh0 + (size_t)(n0 + c) * H_DIM + (kc << 3));
        }
        __syncthreads();
        const int gcol = n0 + cc;

        for (int t = 0; t < T_DIM; ++t) {
            if (t) {
                if (tid < 32) spin1(&flags0[(size_t)(t - 1) * 32 + tid]);
                __syncthreads();
            }
            const unsigned short* hp = t ? out0 + (size_t)(t - 1) * BH : hinit;
            const unsigned short* Ap = hp + (size_t)brow * H_DIM + (g << 3);
            f32x4 acc[2][4];
            #pragma unroll
            for (int a = 0; a < 2; ++a)
                #pragma unroll
                for (int b = 0; b < 4; ++b) acc[a][b] = (f32x4)(0.f);
            short8 ar[16];
            #pragma unroll
            for (int h = 0; h < 2; ++h) {
                #pragma unroll
                for (int i = 0; i < 16; ++i)
                    ar[i] = ldA_sys(Ap + ((h * 16 + i) << 5));
                #pragma unroll
                for (int i = 0; i < 16; ++i) {
                    const char* bp = Bp + (size_t)(h * 16 + i) * 2048;
                    short8 b0 = *reinterpret_cast<const short8*>(bp);
                    short8 b1 = *reinterpret_cast<const short8*>(bp + 256);
                    acc[0][i & 3] = __builtin_amdgcn_mfma_f32_16x16x32_bf16(ar[i], b0, acc[0][i & 3], 0, 0, 0);
                    acc[1][i & 3] = __builtin_amdgcn_mfma_f32_16x16x32_bf16(ar[i], b1, acc[1][i & 3], 0, 0, 0);
                }
            }
            f32x4 s0 = (acc[0][0] + acc[0][1]) + (acc[0][2] + acc[0][3]);
            f32x4 s1 = (acc[1][0] + acc[1][1]) + (acc[1][2] + acc[1][3]);
            // transpose via wave-private LDS scratch (DS is in-order per wave)
            #pragma unroll
            for (int r = 0; r < 4; ++r) {
                sc[(g * 4 + r) * 36 + r0]      = s0[r];
                sc[(g * 4 + r) * 36 + 16 + r0] = s1[r];
            }
            __builtin_amdgcn_sched_barrier(0);
            f32x4 t0 = *reinterpret_cast<const f32x4*>(sc + rr * 36 + cc);
            f32x4 t1 = *reinterpret_cast<const f32x4*>(sc + rr * 36 + cc + 4);
            short8 xv = *reinterpret_cast<const short8*>(
                xp0 + (size_t)t * BH + (size_t)orow * H_DIM + gcol);
            float v[8];
            #pragma unroll
            for (int j = 0; j < 4; ++j) {
                v[j]     = fast_tanh(t0[j] + bf2f((unsigned short)xv[j]));
                v[4 + j] = fast_tanh(t1[j] + bf2f((unsigned short)xv[4 + j]));
            }
            unsigned long long lo = (unsigned long long)f2bf(v[0])
                | ((unsigned long long)f2bf(v[1]) << 16)
                | ((unsigned long long)f2bf(v[2]) << 32)
                | ((unsigned long long)f2bf(v[3]) << 48);
            unsigned long long hi = (unsigned long long)f2bf(v[4])
                | ((unsigned long long)f2bf(v[5]) << 16)
                | ((unsigned long long)f2bf(v[6]) << 32)
                | ((unsigned long long)f2bf(v[7]) << 48);
            unsigned short* o = out0 + (size_t)t * BH + (size_t)orow * H_DIM + gcol;
            st64_sys(o, lo);
            st64_sys(o + 4, hi);
            __syncthreads();  // drains vmcnt: all waves' sc1 stores at MALL
            if (tid == 0)
                __hip_atomic_store(&flags0[(size_t)t * 32 + wg], 1,
                                   __ATOMIC_RELAXED, __HIP_MEMORY_SCOPE_AGENT);
        }
    } else {
        const int wg2 = wg - NW0;
        const int n0 = wg2 << 5;
        for (int i = tid; i < 8192; i += 256) {             // 32 cols x 256 kc
            const int c = i & 31, kc = i >> 5;
            const unsigned short* src = (kc < 128)
                ? wih1 + (size_t)(n0 + c) * H_DIM + (kc << 3)
                : whh1 + (size_t)(n0 + c) * H_DIM + ((kc - 128) << 3);
            *reinterpret_cast<short8*>(smem + (((kc << 5) + c) << 4)) =
                *reinterpret_cast<const short8*>(src);
        }
        __syncthreads();
        const int gcol = n0 + cc;
        const float4 bv0 = *reinterpret_cast<const float4*>(bias1 + gcol);
        const float4 bv1 = *reinterpret_cast<const float4*>(bias1 + gcol + 4);

        for (int t = 0; t < T_DIM; ++t) {
            if (tid < 32) spin1(&flags0[(size_t)t * 32 + tid]);
            else if (t && tid < 64) spin1(&flags1[(size_t)(t - 1) * 32 + (tid - 32)]);
            __syncthreads();
            const unsigned short* a0 = out0 + (size_t)t * BH;
            const unsigned short* h1 = t ? out1 + (size_t)(t - 1) * BH : hinit + BH;
            const unsigned short* ApA = a0 + (size_t)brow * H_DIM + (g << 3);
            const unsigned short* ApH = h1 + (size_t)brow * H_DIM + (g << 3);
            f32x4 acc[2][4];
            #pragma unroll
            for (int a = 0; a < 2; ++a)
                #pragma unroll
                for (int b = 0; b < 4; ++b) acc[a][b] = (f32x4)(0.f);
            short8 ar[16];
            #pragma unroll
            for (int h = 0; h < 4; ++h) {
                const unsigned short* Ap = (h < 2) ? ApA : ApH;
                const int base = (h & 1) << 4;
                #pragma unroll
                for (int i = 0; i < 16; ++i)
                    ar[i] = ldA_sys(Ap + ((base + i) << 5));
                #pragma unroll
                for (int i = 0; i < 16; ++i) {
                    const char* bp = Bp + (size_t)(h * 16 + i) * 2048;
                    short8 b0 = *reinterpret_cast<const short8*>(bp);
                    short8 b1 = *reinterpret_cast<const short8*>(bp + 256);
                    acc[0][i & 3] = __builtin_amdgcn_mfma_f32_16x16x32_bf16(ar[i], b0, acc[0][i & 3], 0, 0, 0);
                    acc[1][i & 3] = __builtin_amdgcn_mfma_f32_16x16x32_bf16(ar[i], b1, acc[1][i & 3], 0, 0, 0);
                }
            }
            f32x4 s0 = (acc[0][0] + acc[0][1]) + (acc[0][2] + acc[0][3]);
            f32x4 s1 = (acc[1][0] + acc[1][1]) + (acc[1][2] + acc[1][3]);
            #pragma unroll
            for (int r = 0; r < 4; ++r) {
                sc[(g * 4 + r) * 36 + r0]      = s0[r];
                sc[(g * 4 + r) * 36 + 16 + r0] = s1[r];
            }
            __builtin_amdgcn_sched_barrier(0);
            f32x4 t0 = *reinterpret_cast<const f32x4*>(sc + rr * 36 + cc);
            f32x4 t1 = *reinterpret_cast<const f32x4*>(sc + rr * 36 + cc + 4);
            float v[8];
            v[0] = fast_tanh(t0[0] + bv0.x); v[1] = fast_tanh(t0[1] + bv0.y);
            v[2] = fast_tanh(t0[2] + bv0.z); v[3] = fast_tanh(t0[3] + bv0.w);
            v[4] = fast_tanh(t1[0] + bv1.x); v[5] = fast_tanh(t1[1] + bv1.y);
            v[6] = fast_tanh(t1[2] + bv1.z); v[7] = fast_tanh(t1[3] + bv1.w);
            unsigned long long lo = (unsigned long long)f2bf(v[0])
                | ((unsigned long long)f2bf(v[1]) << 16)
                | ((unsigned long long)f2bf(v[2]) << 32)
                | ((unsigned long long)f2bf(v[3]) << 48);
            unsigned long long hi = (unsigned long long)f2bf(v[4])
                | ((unsigned long long)f2bf(v[5]) << 16)
                | ((unsigned long long)f2bf(v[6]) << 32)
                | ((unsigned long long)f2bf(v[7]) << 48);
            unsigned short* o = out1 + (size_t)t * BH + (size_t)orow * H_DIM + gcol;
            st64_sys(o, lo);
            st64_sys(o + 4, hi);
            __syncthreads();
            if (tid == 0)
                __hip_atomic_store(&flags1[(size_t)t * 32 + wg2], 1,
                                   __ATOMIC_RELAXED, __HIP_MEMORY_SCOPE_AGENT);
        }
    }
}

// ---------------- launch ----------------
extern "C" void kernel_launch(void* const* d_in, const int* in_sizes, int n_in,
                              void* d_out, int out_size, void* d_ws, size_t ws_size,
                              hipStream_t stream) {
    const float* x      = (const float*)d_in[0];
    const float* hidden = (const float*)d_in[1];
    const float* W_ih0  = (const float*)d_in[2];
    const float* W_hh0  = (const float*)d_in[3];
    const float* b_ih0  = (const float*)d_in[4];
    const float* b_hh0  = (const float*)d_in[5];
    const float* W_ih1  = (const float*)d_in[6];
    const float* W_hh1  = (const float*)d_in[7];
    const float* b_ih1  = (const float*)d_in[8];
    const float* b_hh1  = (const float*)d_in[9];
    const float* W_fc   = (const float*)d_in[10];
    const float* b_fc   = (const float*)d_in[11];

    char* ws = (char*)d_ws;
    size_t off = 0;
    auto alloc = [&](size_t bytes) -> char* {
        char* p = ws + off;
        off += (bytes + 255) & ~(size_t)255;
        return p;
    };
    const size_t TBH = (size_t)T_DIM * B_DIM * H_DIM;
    const size_t TBI = (size_t)T_DIM * B_DIM * I_DIM;

    unsigned short* xb     = (unsigned short*)alloc(TBI * 2);
    unsigned short* wih0b  = (unsigned short*)alloc((size_t)H_DIM * I_DIM * 2);
    unsigned short* whh0b  = (unsigned short*)alloc((size_t)H_DIM * H_DIM * 2);
    unsigned short* wih1b  = (unsigned short*)alloc((size_t)H_DIM * H_DIM * 2);
    unsigned short* whh1b  = (unsigned short*)alloc((size_t)H_DIM * H_DIM * 2);
    unsigned short* wfcb   = (unsigned short*)alloc((size_t)I_DIM * H_DIM * 2);
    unsigned short* hinitb = (unsigned short*)alloc((size_t)2 * B_DIM * H_DIM * 2);
    float* bias0 = (float*)alloc(H_DIM * 4);
    float* bias1 = (float*)alloc(H_DIM * 4);
    unsigned short* xp0    = (unsigned short*)alloc(TBH * 2);
    unsigned short* out0b  = (unsigned short*)alloc(TBH * 2);
    unsigned short* out1b  = (unsigned short*)alloc(TBH * 2);
    int* flags0 = (int*)alloc((size_t)T_DIM * 32 * 4);   // contiguous with flags1
    int* flags1 = (int*)alloc((size_t)T_DIM * 32 * 4);

    auto conv = [&](const float* in, unsigned short* out, int n) {
        int n4 = n / 4;
        int blocks = (n4 + 255) / 256;
        if (blocks > 2048) blocks = 2048;
        conv_f2bf<<<blocks, 256, 0, stream>>>(in, out, n4);
    };
    conv(x, xb, (int)TBI);
    conv(W_ih0, wih0b, H_DIM * I_DIM);
    conv(W_hh0, whh0b, H_DIM * H_DIM);
    conv(W_ih1, wih1b, H_DIM * H_DIM);
    conv(W_fc, wfcb, I_DIM * H_DIM);
    conv(hidden, hinitb, 2 * B_DIM * H_DIM);
    conv(W_hh1, whh1b, H_DIM * H_DIM);
    bias_sum<<<4, 256, 0, stream>>>(b_ih0, b_hh0, bias0, H_DIM);
    bias_sum<<<4, 256, 0, stream>>>(b_ih1, b_hh1, bias1, H_DIM);

    // zero the sync flags (ws is poisoned 0xAA before every timed call)
    (void)hipMemsetAsync(flags0, 0, (size_t)T_DIM * 32 * 4 * 2, stream);

    // xp0 = xb @ wih0b^T + (b_ih0 + b_hh0)   [32768 x 1024], K=512, bf16 out
    {
        int M = T_DIM * B_DIM, N = H_DIM, K = I_DIM;
        dim3 grid((M / 64) * (N / 64));
        gemm_bias<1><<<grid, 256, 0, stream>>>(xb, wih0b, bias0, xp0, M, N, K);
    }

    // persistent cooperative recurrence (both layers, pipelined via flags)
    {
        void* args[] = {(void*)&xp0, (void*)&whh0b, (void*)&wih1b, (void*)&whh1b,
                        (void*)&bias1, (void*)&hinitb, (void*)&out0b, (void*)&out1b,
                        (void*)&flags0, (void*)&flags1};
        (void)hipLaunchCooperativeKernel(reinterpret_cast<void*>(rnn_persist),
                                         dim3(NW0 + NW1), dim3(256), args, 0, stream);
    }

    // out = out1 @ W_fc^T + b_fc   [32768 x 512], K=1024, f32 out
    {
        int M = T_DIM * B_DIM, N = I_DIM, K = H_DIM;
        dim3 grid((M / 64) * (N / 64));
        gemm_bias<0><<<grid, 256, 0, stream>>>(out1b, wfcb, b_fc, d_out, M, N, K);
    }
}

// Round 12
// 7325.208 us; speedup vs baseline: 1.1942x; 1.1942x over previous
//
#include <hip/hip_runtime.h>
#include <stdint.h>

#define T_DIM 512
#define B_DIM 64
#define I_DIM 512
#define H_DIM 1024
#define BH ((size_t)B_DIM * H_DIM)
#define NW0 32   // layer-0 workgroups, 32 output cols each
#define NW1 32   // layer-1 workgroups, 32 output cols each

typedef __attribute__((ext_vector_type(8))) short short8;
typedef __attribute__((ext_vector_type(4))) float f32x4;

__device__ __forceinline__ unsigned short f2bf(float f) {
    unsigned int u = __float_as_uint(f);
    unsigned int r = (u + 0x7FFFu + ((u >> 16) & 1u)) >> 16;
    return (unsigned short)r;
}
__device__ __forceinline__ float bf2f(unsigned short b) {
    return __uint_as_float(((unsigned int)b) << 16);
}
__device__ __forceinline__ float fast_tanh(float x) {
    x = fminf(fmaxf(x, -15.f), 15.f);
    float e = __expf(2.f * x);
    return (e - 1.f) / (e + 1.f);
}

// write-through (sc0 sc1) 16B store: data visible at MALL once vmcnt drains,
// L2 stays clean -> release needs NO buffer_wbl2.
__device__ __forceinline__ void st128_wt(unsigned short* p, short8 v) {
    asm volatile("global_store_dwordx4 %0, %1, off sc0 sc1" :: "v"(p), "v"(v) : "memory");
}
__device__ __forceinline__ void acquire_inv() {
#if __has_builtin(__builtin_amdgcn_fence)
    __builtin_amdgcn_fence(__ATOMIC_ACQUIRE, "agent");   // buffer_inv only (no wb)
#else
    __threadfence();
#endif
}
__device__ __forceinline__ void drain_stores() {
    asm volatile("s_waitcnt vmcnt(0)" ::: "memory");
}
__device__ __forceinline__ void spin1(const int* f) {
    while (__hip_atomic_load(f, __ATOMIC_RELAXED, __HIP_MEMORY_SCOPE_AGENT) == 0)
        __builtin_amdgcn_s_sleep(4);
}

// ---------------- f32 -> bf16 convert, vectorized x4 ----------------
__global__ void conv_f2bf(const float* __restrict__ in, unsigned short* __restrict__ out, int n4) {
    int i = blockIdx.x * blockDim.x + threadIdx.x;
    int stride = gridDim.x * blockDim.x;
    for (int idx = i; idx < n4; idx += stride) {
        float4 v = reinterpret_cast<const float4*>(in)[idx];
        ushort4 o;
        o.x = f2bf(v.x); o.y = f2bf(v.y); o.z = f2bf(v.z); o.w = f2bf(v.w);
        reinterpret_cast<ushort4*>(out)[idx] = o;
    }
}

__global__ void bias_sum(const float* __restrict__ a, const float* __restrict__ b,
                         float* __restrict__ o, int n) {
    int i = blockIdx.x * blockDim.x + threadIdx.x;
    if (i < n) o[i] = a[i] + b[i];
}

// ---------------- GEMM: C[M,N] = A[M,K] @ W[N,K]^T + bias[N] ----------------
template <int OUT_BF16>
__global__ void gemm_bias(const unsigned short* __restrict__ A,
                          const unsigned short* __restrict__ W,
                          const float* __restrict__ bias,
                          void* __restrict__ Cout,
                          int M, int N, int K) {
    const int ntn = N >> 6;
    const int mt = blockIdx.x / ntn;
    const int nt = blockIdx.x % ntn;
    const int m_base = mt << 6, n_base = nt << 6;
    const int lane = threadIdx.x & 63;
    const int wave = threadIdx.x >> 6;
    const int wm = wave >> 1, wn = wave & 1;
    const int r0 = lane & 15;
    const int g  = lane >> 4;
    const int koff = g << 3;

    f32x4 acc[2][2];
    for (int i = 0; i < 2; i++)
        for (int j = 0; j < 2; j++)
            acc[i][j] = (f32x4)(0.f);

    const unsigned short* Arow0 = A + (size_t)(m_base + wm * 32 + r0) * K + koff;
    const unsigned short* Wrow0 = W + (size_t)(n_base + wn * 32 + r0) * K + koff;

    for (int k0 = 0; k0 < K; k0 += 32) {
        short8 a0 = *reinterpret_cast<const short8*>(Arow0 + k0);
        short8 a1 = *reinterpret_cast<const short8*>(Arow0 + (size_t)16 * K + k0);
        short8 b0 = *reinterpret_cast<const short8*>(Wrow0 + k0);
        short8 b1 = *reinterpret_cast<const short8*>(Wrow0 + (size_t)16 * K + k0);
        acc[0][0] = __builtin_amdgcn_mfma_f32_16x16x32_bf16(a0, b0, acc[0][0], 0, 0, 0);
        acc[0][1] = __builtin_amdgcn_mfma_f32_16x16x32_bf16(a0, b1, acc[0][1], 0, 0, 0);
        acc[1][0] = __builtin_amdgcn_mfma_f32_16x16x32_bf16(a1, b0, acc[1][0], 0, 0, 0);
        acc[1][1] = __builtin_amdgcn_mfma_f32_16x16x32_bf16(a1, b1, acc[1][1], 0, 0, 0);
    }

    for (int mi = 0; mi < 2; mi++) {
        for (int ni = 0; ni < 2; ni++) {
            for (int r = 0; r < 4; r++) {
                int row = m_base + wm * 32 + mi * 16 + g * 4 + r;
                int col = n_base + wn * 32 + ni * 16 + r0;
                float v = acc[mi][ni][r] + bias[col];
                if (OUT_BF16)
                    ((unsigned short*)Cout)[(size_t)row * N + col] = f2bf(v);
                else
                    ((float*)Cout)[(size_t)row * N + col] = v;
            }
        }
    }
}

// ---------------- persistent pipelined 2-layer RNN recurrence ----------------
// 64 wgs x 256 thr, cooperative. wg<32: layer0 (32 cols). wg>=32: layer1.
// h-state protocol: producers store via write-through sc0/sc1 dwordx4 (visible
// at MALL at vmcnt==0, L2 clean); consumers flag-wait, then acquire-fence
// (buffer_inv: L1+L2 tag invalidate, no writeback) and use NORMAL cached
// wide loads -> L2 serves the 8 wgs/XCD from one MALL fetch per line.
__global__ void __launch_bounds__(256, 1)
rnn_persist(const unsigned short* __restrict__ xp0,
            const unsigned short* __restrict__ whh0,
            const unsigned short* __restrict__ wih1,
            const unsigned short* __restrict__ whh1,
            const float* __restrict__ bias1,
            const unsigned short* __restrict__ hinit,
            unsigned short* __restrict__ out0,
            unsigned short* __restrict__ out1,
            int* __restrict__ flags0,
            int* __restrict__ flags1)
{
    __shared__ __attribute__((aligned(16))) char smem[140288];  // 128K weights + 9K scratch
    const int tid  = threadIdx.x;
    const int lane = tid & 63;
    const int wave = tid >> 6;
    const int r0 = lane & 15;
    const int g  = lane >> 4;
    const int wg = blockIdx.x;
    const int brow = (wave << 4) + r0;

    const char* Bp = smem + (g << 9) + (r0 << 4);          // + s*2048 + nf*256
    float* sc = (float*)(smem + 131072) + wave * 576;       // 16 rows x 36 f32
    const int rr = lane >> 2;                               // epilogue row 0..15
    const int cc = (lane & 3) << 3;                         // epilogue col base (8 wide)
    const int orow = (wave << 4) + rr;

    if (wg < NW0) {
        const int n0 = wg << 5;
        for (int i = tid; i < 4096; i += 256) {             // 32 cols x 128 kc
            const int c = i & 31, kc = i >> 5;
            *reinterpret_cast<short8*>(smem + (((kc << 5) + c) << 4)) =
                *reinterpret_cast<const short8*>(whh0 + (size_t)(n0 + c) * H_DIM + (kc << 3));
        }
        __syncthreads();
        const int gcol = n0 + cc;

        for (int t = 0; t < T_DIM; ++t) {
            if (t) {
                if (tid < 32) spin1(&flags0[(size_t)(t - 1) * 32 + tid]);
                __syncthreads();
                acquire_inv();
            }
            const unsigned short* hp = t ? out0 + (size_t)(t - 1) * BH : hinit;
            const unsigned short* Ap = hp + (size_t)brow * H_DIM + (g << 3);
            f32x4 acc[2][4];
            #pragma unroll
            for (int a = 0; a < 2; ++a)
                #pragma unroll
                for (int b = 0; b < 4; ++b) acc[a][b] = (f32x4)(0.f);
            short8 ar[16];
            #pragma unroll
            for (int h = 0; h < 2; ++h) {
                #pragma unroll
                for (int i = 0; i < 16; ++i)
                    ar[i] = *reinterpret_cast<const short8*>(Ap + ((h * 16 + i) << 5));
                #pragma unroll
                for (int i = 0; i < 16; ++i) {
                    const char* bp = Bp + (size_t)(h * 16 + i) * 2048;
                    short8 b0 = *reinterpret_cast<const short8*>(bp);
                    short8 b1 = *reinterpret_cast<const short8*>(bp + 256);
                    acc[0][i & 3] = __builtin_amdgcn_mfma_f32_16x16x32_bf16(ar[i], b0, acc[0][i & 3], 0, 0, 0);
                    acc[1][i & 3] = __builtin_amdgcn_mfma_f32_16x16x32_bf16(ar[i], b1, acc[1][i & 3], 0, 0, 0);
                }
            }
            f32x4 s0 = (acc[0][0] + acc[0][1]) + (acc[0][2] + acc[0][3]);
            f32x4 s1 = (acc[1][0] + acc[1][1]) + (acc[1][2] + acc[1][3]);
            // transpose via wave-private LDS scratch (DS is in-order per wave)
            #pragma unroll
            for (int r = 0; r < 4; ++r) {
                sc[(g * 4 + r) * 36 + r0]      = s0[r];
                sc[(g * 4 + r) * 36 + 16 + r0] = s1[r];
            }
            __builtin_amdgcn_sched_barrier(0);
            f32x4 t0 = *reinterpret_cast<const f32x4*>(sc + rr * 36 + cc);
            f32x4 t1 = *reinterpret_cast<const f32x4*>(sc + rr * 36 + cc + 4);
            short8 xv = *reinterpret_cast<const short8*>(
                xp0 + (size_t)t * BH + (size_t)orow * H_DIM + gcol);
            short8 ov;
            #pragma unroll
            for (int j = 0; j < 4; ++j) {
                ov[j]     = (short)f2bf(fast_tanh(t0[j] + bf2f((unsigned short)xv[j])));
                ov[4 + j] = (short)f2bf(fast_tanh(t1[j] + bf2f((unsigned short)xv[4 + j])));
            }
            st128_wt(out0 + (size_t)t * BH + (size_t)orow * H_DIM + gcol, ov);
            drain_stores();   // sc1 stores ACKed at MALL
            __syncthreads();
            if (tid == 0)
                __hip_atomic_store(&flags0[(size_t)t * 32 + wg], 1,
                                   __ATOMIC_RELAXED, __HIP_MEMORY_SCOPE_AGENT);
        }
    } else {
        const int wg2 = wg - NW0;
        const int n0 = wg2 << 5;
        for (int i = tid; i < 8192; i += 256) {             // 32 cols x 256 kc
            const int c = i & 31, kc = i >> 5;
            const unsigned short* src = (kc < 128)
                ? wih1 + (size_t)(n0 + c) * H_DIM + (kc << 3)
                : whh1 + (size_t)(n0 + c) * H_DIM + ((kc - 128) << 3);
            *reinterpret_cast<short8*>(smem + (((kc << 5) + c) << 4)) =
                *reinterpret_cast<const short8*>(src);
        }
        __syncthreads();
        const int gcol = n0 + cc;
        const float4 bv0 = *reinterpret_cast<const float4*>(bias1 + gcol);
        const float4 bv1 = *reinterpret_cast<const float4*>(bias1 + gcol + 4);

        for (int t = 0; t < T_DIM; ++t) {
            if (tid < 32) spin1(&flags0[(size_t)t * 32 + tid]);
            else if (t && tid < 64) spin1(&flags1[(size_t)(t - 1) * 32 + (tid - 32)]);
            __syncthreads();
            acquire_inv();
            const unsigned short* a0 = out0 + (size_t)t * BH;
            const unsigned short* h1 = t ? out1 + (size_t)(t - 1) * BH : hinit + BH;
            const unsigned short* ApA = a0 + (size_t)brow * H_DIM + (g << 3);
            const unsigned short* ApH = h1 + (size_t)brow * H_DIM + (g << 3);
            f32x4 acc[2][4];
            #pragma unroll
            for (int a = 0; a < 2; ++a)
                #pragma unroll
                for (int b = 0; b < 4; ++b) acc[a][b] = (f32x4)(0.f);
            short8 ar[16];
            #pragma unroll
            for (int h = 0; h < 4; ++h) {
                const unsigned short* Ap = (h < 2) ? ApA : ApH;
                const int base = (h & 1) << 4;
                #pragma unroll
                for (int i = 0; i < 16; ++i)
                    ar[i] = *reinterpret_cast<const short8*>(Ap + ((base + i) << 5));
                #pragma unroll
                for (int i = 0; i < 16; ++i) {
                    const char* bp = Bp + (size_t)(h * 16 + i) * 2048;
                    short8 b0 = *reinterpret_cast<const short8*>(bp);
                    short8 b1 = *reinterpret_cast<const short8*>(bp + 256);
                    acc[0][i & 3] = __builtin_amdgcn_mfma_f32_16x16x32_bf16(ar[i], b0, acc[0][i & 3], 0, 0, 0);
                    acc[1][i & 3] = __builtin_amdgcn_mfma_f32_16x16x32_bf16(ar[i], b1, acc[1][i & 3], 0, 0, 0);
                }
            }
            f32x4 s0 = (acc[0][0] + acc[0][1]) + (acc[0][2] + acc[0][3]);
            f32x4 s1 = (acc[1][0] + acc[1][1]) + (acc[1][2] + acc[1][3]);
            #pragma unroll
            for (int r = 0; r < 4; ++r) {
                sc[(g * 4 + r) * 36 + r0]      = s0[r];
                sc[(g * 4 + r) * 36 + 16 + r0] = s1[r];
            }
            __builtin_amdgcn_sched_barrier(0);
            f32x4 t0 = *reinterpret_cast<const f32x4*>(sc + rr * 36 + cc);
            f32x4 t1 = *reinterpret_cast<const f32x4*>(sc + rr * 36 + cc + 4);
            short8 ov;
            ov[0] = (short)f2bf(fast_tanh(t0[0] + bv0.x));
            ov[1] = (short)f2bf(fast_tanh(t0[1] + bv0.y));
            ov[2] = (short)f2bf(fast_tanh(t0[2] + bv0.z));
            ov[3] = (short)f2bf(fast_tanh(t0[3] + bv0.w));
            ov[4] = (short)f2bf(fast_tanh(t1[0] + bv1.x));
            ov[5] = (short)f2bf(fast_tanh(t1[1] + bv1.y));
            ov[6] = (short)f2bf(fast_tanh(t1[2] + bv1.z));
            ov[7] = (short)f2bf(fast_tanh(t1[3] + bv1.w));
            st128_wt(out1 + (size_t)t * BH + (size_t)orow * H_DIM + gcol, ov);
            drain_stores();
            __syncthreads();
            if (tid == 0)
                __hip_atomic_store(&flags1[(size_t)t * 32 + wg2], 1,
                                   __ATOMIC_RELAXED, __HIP_MEMORY_SCOPE_AGENT);
        }
    }
}

// ---------------- launch ----------------
extern "C" void kernel_launch(void* const* d_in, const int* in_sizes, int n_in,
                              void* d_out, int out_size, void* d_ws, size_t ws_size,
                              hipStream_t stream) {
    const float* x      = (const float*)d_in[0];
    const float* hidden = (const float*)d_in[1];
    const float* W_ih0  = (const float*)d_in[2];
    const float* W_hh0  = (const float*)d_in[3];
    const float* b_ih0  = (const float*)d_in[4];
    const float* b_hh0  = (const float*)d_in[5];
    const float* W_ih1  = (const float*)d_in[6];
    const float* W_hh1  = (const float*)d_in[7];
    const float* b_ih1  = (const float*)d_in[8];
    const float* b_hh1  = (const float*)d_in[9];
    const float* W_fc   = (const float*)d_in[10];
    const float* b_fc   = (const float*)d_in[11];

    char* ws = (char*)d_ws;
    size_t off = 0;
    auto alloc = [&](size_t bytes) -> char* {
        char* p = ws + off;
        off += (bytes + 255) & ~(size_t)255;
        return p;
    };
    const size_t TBH = (size_t)T_DIM * B_DIM * H_DIM;
    const size_t TBI = (size_t)T_DIM * B_DIM * I_DIM;

    unsigned short* xb     = (unsigned short*)alloc(TBI * 2);
    unsigned short* wih0b  = (unsigned short*)alloc((size_t)H_DIM * I_DIM * 2);
    unsigned short* whh0b  = (unsigned short*)alloc((size_t)H_DIM * H_DIM * 2);
    unsigned short* wih1b  = (unsigned short*)alloc((size_t)H_DIM * H_DIM * 2);
    unsigned short* whh1b  = (unsigned short*)alloc((size_t)H_DIM * H_DIM * 2);
    unsigned short* wfcb   = (unsigned short*)alloc((size_t)I_DIM * H_DIM * 2);
    unsigned short* hinitb = (unsigned short*)alloc((size_t)2 * B_DIM * H_DIM * 2);
    float* bias0 = (float*)alloc(H_DIM * 4);
    float* bias1 = (float*)alloc(H_DIM * 4);
    unsigned short* xp0    = (unsigned short*)alloc(TBH * 2);
    unsigned short* out0b  = (unsigned short*)alloc(TBH * 2);
    unsigned short* out1b  = (unsigned short*)alloc(TBH * 2);
    int* flags0 = (int*)alloc((size_t)T_DIM * 32 * 4);   // contiguous with flags1
    int* flags1 = (int*)alloc((size_t)T_DIM * 32 * 4);

    auto conv = [&](const float* in, unsigned short* out, int n) {
        int n4 = n / 4;
        int blocks = (n4 + 255) / 256;
        if (blocks > 2048) blocks = 2048;
        conv_f2bf<<<blocks, 256, 0, stream>>>(in, out, n4);
    };
    conv(x, xb, (int)TBI);
    conv(W_ih0, wih0b, H_DIM * I_DIM);
    conv(W_hh0, whh0b, H_DIM * H_DIM);
    conv(W_ih1, wih1b, H_DIM * H_DIM);
    conv(W_fc, wfcb, I_DIM * H_DIM);
    conv(hidden, hinitb, 2 * B_DIM * H_DIM);
    conv(W_hh1, whh1b, H_DIM * H_DIM);
    bias_sum<<<4, 256, 0, stream>>>(b_ih0, b_hh0, bias0, H_DIM);
    bias_sum<<<4, 256, 0, stream>>>(b_ih1, b_hh1, bias1, H_DIM);

    // zero the sync flags (ws is poisoned 0xAA before every timed call)
    (void)hipMemsetAsync(flags0, 0, (size_t)T_DIM * 32 * 4 * 2, stream);

    // xp0 = xb @ wih0b^T + (b_ih0 + b_hh0)   [32768 x 1024], K=512, bf16 out
    {
        int M = T_DIM * B_DIM, N = H_DIM, K = I_DIM;
        dim3 grid((M / 64) * (N / 64));
        gemm_bias<1><<<grid, 256, 0, stream>>>(xb, wih0b, bias0, xp0, M, N, K);
    }

    // persistent cooperative recurrence (both layers, pipelined via flags)
    {
        void* args[] = {(void*)&xp0, (void*)&whh0b, (void*)&wih1b, (void*)&whh1b,
                        (void*)&bias1, (void*)&hinitb, (void*)&out0b, (void*)&out1b,
                        (void*)&flags0, (void*)&flags1};
        (void)hipLaunchCooperativeKernel(reinterpret_cast<void*>(rnn_persist),
                                         dim3(NW0 + NW1), dim3(256), args, 0, stream);
    }

    // out = out1 @ W_fc^T + b_fc   [32768 x 512], K=1024, f32 out
    {
        int M = T_DIM * B_DIM, N = I_DIM, K = H_DIM;
        dim3 grid((M / 64) * (N / 64));
        gemm_bias<0><<<grid, 256, 0, stream>>>(out1b, wfcb, b_fc, d_out, M, N, K);
    }
}